// Round 7
// baseline (248.341 us; speedup 1.0000x reference)
//
#include <hip/hip_runtime.h>
#include <hip/hip_bf16.h>

#define N_NODES 50000
#define N_EDGES 800000
#define DIM 256      // input feature dim = K
#define QKDIM 256    // packed q|k per node (fp8: 256 B/row)
// pre = (0.5/H) * sum_A (q_s k_d + q_d k_s) = (full rotated 256-dot)/16

typedef __bf16 bfrag  __attribute__((ext_vector_type(8)));
typedef __bf16 bf4    __attribute__((ext_vector_type(4)));
typedef float  ffrag  __attribute__((ext_vector_type(4)));
typedef float  f2     __attribute__((ext_vector_type(2)));

#define EP_PITCH 272   // epilogue LDS byte pitch (256+16)

// ---------------- prep: W' fp32->bf16 + zero diagA0 region ----------------
__global__ __launch_bounds__(256) void prep_kernel(
    const float* __restrict__ Wq, const float* __restrict__ Wk,
    __bf16* __restrict__ Wb, float* __restrict__ out)
{
    const int tid = blockIdx.x * 256 + threadIdx.x;   // 0..16383
    const int i = tid * 4;                            // 65536 elems total
    const float* s = (i < 32768) ? (Wq + i) : (Wk + (i - 32768));
    const float4 v = *(const float4*)s;
    bf4 o;
    o[0] = (__bf16)v.x; o[1] = (__bf16)v.y; o[2] = (__bf16)v.z; o[3] = (__bf16)v.w;
    *(bf4*)(Wb + i) = o;

    if (i + 4 <= N_NODES)   // 50000 % 4 == 0, covers exactly
        *(float4*)(out + i) = make_float4(0.f, 0.f, 0.f, 0.f);
}

// ---------------- Projection via MFMA bf16 ----------------
// Block: 64 nodes x 256 cols, 4 waves; wave wv covers cols [64wv, 64wv+64).
// A staged in LDS in fragment order; B preloaded to regs per K-half;
// epilogue via LDS transpose -> coalesced dwordx4 stores.  [identical to R6]
__global__ __launch_bounds__(256) void proj_mfma(
    const float* __restrict__ x,
    const __bf16* __restrict__ Wb,
    const float* __restrict__ bq, const float* __restrict__ bk,
    unsigned char* __restrict__ qk8)
{
    __shared__ __bf16 As[64 * 256];   // 32 KB, fragment-order; reused by epilogue

    const int tid  = threadIdx.x;
    const int wv   = tid >> 6;         // 0..3 -> 64-col slice
    const int lane = tid & 63;
    const int m    = lane & 15;
    const int q    = lane >> 4;
    const int mbase = blockIdx.x * 64;

    // ---- stage A (64 rows x 256 k fp32 -> bf16 frags) ----
    {
        const int srow = tid >> 2;           // 0..63
        const int c4   = tid & 3;
        int grow = mbase + srow;
        grow = grow < N_NODES ? grow : N_NODES - 1;
        const float* xp = x + (size_t)grow * DIM;
        const int mt_ = srow >> 4, m_ = srow & 15;
        #pragma unroll
        for (int i = 0; i < 16; ++i) {
            const int k = c4 * 4 + 16 * i;
            const float4 v = *(const float4*)(xp + k);
            bf4 o;
            o[0] = (__bf16)v.x; o[1] = (__bf16)v.y;
            o[2] = (__bf16)v.z; o[3] = (__bf16)v.w;
            const int seg = (k >> 5) * 4 + mt_;
            const int ln  = ((k >> 3) & 3) * 16 + m_;
            *(bf4*)(As + seg * 512 + ln * 8 + (k & 7)) = o;
        }
    }
    __syncthreads();

    ffrag acc[4][4] = {};              // [m-tile][n-tile]

    #pragma unroll
    for (int h = 0; h < 2; ++h) {
        bfrag b[4][4];                 // [k-step][n-tile]
        #pragma unroll
        for (int sp = 0; sp < 4; ++sp)
            #pragma unroll
            for (int nt = 0; nt < 4; ++nt) {
                const int col = wv * 64 + nt * 16 + m;
                b[sp][nt] = *(const bfrag*)(Wb + (size_t)col * DIM
                                            + 32 * (4 * h + sp) + 8 * q);
            }
        #pragma unroll
        for (int sp = 0; sp < 4; ++sp) {
            bfrag a[4];
            #pragma unroll
            for (int mt = 0; mt < 4; ++mt)
                a[mt] = *(const bfrag*)(As + ((4 * h + sp) * 4 + mt) * 512 + lane * 8);
            #pragma unroll
            for (int mt = 0; mt < 4; ++mt)
                #pragma unroll
                for (int nt = 0; nt < 4; ++nt)
                    acc[mt][nt] = __builtin_amdgcn_mfma_f32_16x16x32_bf16(
                                      a[mt], b[sp][nt], acc[mt][nt], 0, 0, 0);
        }
    }

    // ---- epilogue: fp8-encode into LDS (transpose), then coalesced stores
    __syncthreads();                    // all waves done reading As
    unsigned char* ep = (unsigned char*)As;   // [64][EP_PITCH] bytes, 17 KB
    #pragma unroll
    for (int nt = 0; nt < 4; ++nt) {
        const int col  = wv * 64 + nt * 16 + m;
        const float bias = (col < 128) ? bq[col] : bk[col - 128];
        #pragma unroll
        for (int mt = 0; mt < 4; ++mt) {
            #pragma unroll
            for (int r = 0; r < 4; ++r) {
                const int rl = mt * 16 + q * 4 + r;
                const float v = acc[mt][nt][r] + bias;
                const int pk = __builtin_amdgcn_cvt_pk_fp8_f32(v, v, 0, false);
                ep[rl * EP_PITCH + col] = (unsigned char)(pk & 0xFF);
            }
        }
    }
    __syncthreads();
    {
        const int rl = tid >> 2;              // 0..63
        const int ch = tid & 3;               // 64-B chunk
        const int grow = mbase + rl;
        if (grow < N_NODES) {
            const uint4* s4 = (const uint4*)(ep + rl * EP_PITCH + ch * 64);
            const uint4 t0 = s4[0], t1 = s4[1], t2 = s4[2], t3 = s4[3];
            uint4* g = (uint4*)(qk8 + (size_t)grow * QKDIM + ch * 64);
            g[0] = t0; g[1] = t1; g[2] = t2; g[3] = t3;
        }
    }
}

// ---------------- Edge scoring + scatter (fp8, 2 lanes/edge) ----------------
// 32 edges/wave. Lanes 0-31 = half j=0 (src bytes [0,128)), lanes 32-63 =
// j=1 (src bytes [128,256)). Rotation (t+128)&255: src half j pairs with
// dst half j^1. 16 outstanding 16-B loads per lane for latency hiding.
__global__ __launch_bounds__(256) void edge_kernel(
    const unsigned char* __restrict__ qk8,
    const int* __restrict__ edge_index,   // [2][E]
    const int* __restrict__ d0,           // d0_index row 1, [2E]
    float* __restrict__ out)              // [0..N)=diagA0 (pre-zeroed), [N..N+E)=diagA1
{
    const int wave = (blockIdx.x * blockDim.x + threadIdx.x) >> 6;
    const int lane = threadIdx.x & 63;
    const int g = lane & 31;              // edge within wave
    const int j = lane >> 5;              // half (0/1)
    const int e = wave * 32 + g;          // 800000 = 25000*32, no tail

    const int src = edge_index[e];
    const int dst = edge_index[N_EDGES + e];

    const uint4* rs = (const uint4*)(qk8 + (size_t)src * QKDIM + 128 * j);
    const uint4* rd = (const uint4*)(qk8 + (size_t)dst * QKDIM + 128 * (j ^ 1));

    uint4 a[8], b[8];
    #pragma unroll
    for (int t = 0; t < 8; ++t) a[t] = rs[t];
    #pragma unroll
    for (int t = 0; t < 8; ++t) b[t] = rd[t];

    f2 p2 = {0.f, 0.f};
    #pragma unroll
    for (int t = 0; t < 8; ++t) {
        const unsigned int* ua = (const unsigned int*)&a[t];
        const unsigned int* ub = (const unsigned int*)&b[t];
        #pragma unroll
        for (int w = 0; w < 4; ++w) {
            p2 += __builtin_amdgcn_cvt_pk_f32_fp8(ua[w], false)
                * __builtin_amdgcn_cvt_pk_f32_fp8(ub[w], false);
            p2 += __builtin_amdgcn_cvt_pk_f32_fp8(ua[w], true)
                * __builtin_amdgcn_cvt_pk_f32_fp8(ub[w], true);
        }
    }
    float p = p2[0] + p2[1];
    p += __shfl_xor(p, 32, 64);           // combine the two halves

    const int2 tg = *(const int2*)(d0 + 2 * e);
    const float val = __expf(p * 0.0625f);   // /16 = 0.5 * mean over 8 heads

    if (j == 0) {
        out[N_NODES + e] = val;           // diagA1, coalesced over lanes 0-31
        atomicAdd(&out[tg.x], val);
    } else {
        atomicAdd(&out[tg.y], val);
    }
}

extern "C" void kernel_launch(void* const* d_in, const int* in_sizes, int n_in,
                              void* d_out, int out_size, void* d_ws, size_t ws_size,
                              hipStream_t stream) {
    const float* x  = (const float*)d_in[0];
    const float* Wq = (const float*)d_in[1];
    const float* bq = (const float*)d_in[2];
    const float* Wk = (const float*)d_in[3];
    const float* bk = (const float*)d_in[4];
    const int* edge_index = (const int*)d_in[5];
    const int* d0 = (const int*)d_in[6] + 2 * N_EDGES;  // row 1 of d0_index
    float* out = (float*)d_out;

    unsigned char* qk8 = (unsigned char*)d_ws;                       // 12.8 MB
    __bf16* Wb = (__bf16*)((char*)d_ws + (size_t)N_NODES * QKDIM);   // +128 KB

    prep_kernel<<<64, 256, 0, stream>>>(Wq, Wk, Wb, out);

    // MEASUREMENT PROBE (this round only): proj is idempotent; launching it
    // twice lets us read its true duration as total - (known fixed + edge).
    proj_mfma<<<(N_NODES + 63) / 64, 256, 0, stream>>>(x, Wb, bq, bk, qk8);
    proj_mfma<<<(N_NODES + 63) / 64, 256, 0, stream>>>(x, Wb, bq, bk, qk8);

    // 2 lanes/edge, 32 edges/wave, 4 waves/block -> 128 edges/block
    edge_kernel<<<N_EDGES / 128, 256, 0, stream>>>(qk8, edge_index, d0, out);
}

// Round 8
// 227.431 us; speedup vs baseline: 1.0919x; 1.0919x over previous
//
#include <hip/hip_runtime.h>
#include <hip/hip_bf16.h>

#define N_NODES 50000
#define N_EDGES 800000
#define DIM 256      // input feature dim = K
#define QKDIM 256    // packed q|k per node (fp8: 256 B/row)
// pre = (0.5/H) * sum_A (q_s k_d + q_d k_s) = (full rotated 256-dot)/16

typedef __bf16 bfrag  __attribute__((ext_vector_type(8)));
typedef __bf16 bf4    __attribute__((ext_vector_type(4)));
typedef float  ffrag  __attribute__((ext_vector_type(4)));
typedef float  f2     __attribute__((ext_vector_type(2)));

#define EP_PITCH 272   // epilogue LDS byte pitch (256+16)

// ---------------- Projection via MFMA bf16 (prep fused in) ----------------
// Block: 64 nodes x 256 cols, 4 waves; wave wv covers cols [64wv, 64wv+64).
// A staged in LDS in fragment order; B converted fp32->bf16 in-register per
// K-half (no separate prep kernel / Wb buffer); out[0..N) zeroing distributed
// across blocks; epilogue via LDS transpose -> coalesced dwordx4 stores.
__global__ __launch_bounds__(256) void proj_mfma(
    const float* __restrict__ x,
    const float* __restrict__ Wq, const float* __restrict__ bq,
    const float* __restrict__ Wk, const float* __restrict__ bk,
    unsigned char* __restrict__ qk8, float* __restrict__ out)
{
    __shared__ __bf16 As[64 * 256];   // 32 KB, fragment-order; reused by epilogue

    const int tid  = threadIdx.x;
    const int wv   = tid >> 6;         // 0..3 -> 64-col slice
    const int lane = tid & 63;
    const int m    = lane & 15;
    const int q    = lane >> 4;
    const int mbase = blockIdx.x * 64;

    // ---- fused prep: zero diagA0 region (782 blocks x 64 floats >= 50000)
    if (tid < 16) {
        const int base = blockIdx.x * 64 + tid * 4;
        if (base + 4 <= N_NODES) {
            *(float4*)(out + base) = make_float4(0.f, 0.f, 0.f, 0.f);
        } else {
            for (int t = base; t < N_NODES; ++t) out[t] = 0.f;
        }
    }

    // ---- stage A (64 rows x 256 k fp32 -> bf16 frags) ----
    {
        const int srow = tid >> 2;           // 0..63
        const int c4   = tid & 3;
        int grow = mbase + srow;
        grow = grow < N_NODES ? grow : N_NODES - 1;
        const float* xp = x + (size_t)grow * DIM;
        const int mt_ = srow >> 4, m_ = srow & 15;
        #pragma unroll
        for (int i = 0; i < 16; ++i) {
            const int k = c4 * 4 + 16 * i;
            const float4 v = *(const float4*)(xp + k);
            bf4 o;
            o[0] = (__bf16)v.x; o[1] = (__bf16)v.y;
            o[2] = (__bf16)v.z; o[3] = (__bf16)v.w;
            const int seg = (k >> 5) * 4 + mt_;
            const int ln  = ((k >> 3) & 3) * 16 + m_;
            *(bf4*)(As + seg * 512 + ln * 8 + (k & 7)) = o;
        }
    }
    __syncthreads();

    // per-wave W column pointers (fixed per nt across the K loop)
    const float* wcol[4];
    #pragma unroll
    for (int nt = 0; nt < 4; ++nt) {
        const int col = wv * 64 + nt * 16 + m;
        wcol[nt] = (col < 128) ? (Wq + (size_t)col * DIM)
                               : (Wk + (size_t)(col - 128) * DIM);
    }

    ffrag acc[4][4] = {};              // [m-tile][n-tile]

    #pragma unroll
    for (int h = 0; h < 2; ++h) {
        // convert this K-half's B fragments fp32->bf16 in-register
        bfrag b[4][4];                 // [k-step][n-tile]
        #pragma unroll
        for (int sp = 0; sp < 4; ++sp)
            #pragma unroll
            for (int nt = 0; nt < 4; ++nt) {
                const float* wp = wcol[nt] + 32 * (4 * h + sp) + 8 * q;
                const float4 lo = *(const float4*)wp;
                const float4 hi = *(const float4*)(wp + 4);
                bfrag t;
                t[0] = (__bf16)lo.x; t[1] = (__bf16)lo.y;
                t[2] = (__bf16)lo.z; t[3] = (__bf16)lo.w;
                t[4] = (__bf16)hi.x; t[5] = (__bf16)hi.y;
                t[6] = (__bf16)hi.z; t[7] = (__bf16)hi.w;
                b[sp][nt] = t;
            }
        #pragma unroll
        for (int sp = 0; sp < 4; ++sp) {
            bfrag a[4];
            #pragma unroll
            for (int mt = 0; mt < 4; ++mt)
                a[mt] = *(const bfrag*)(As + ((4 * h + sp) * 4 + mt) * 512 + lane * 8);
            #pragma unroll
            for (int mt = 0; mt < 4; ++mt)
                #pragma unroll
                for (int nt = 0; nt < 4; ++nt)
                    acc[mt][nt] = __builtin_amdgcn_mfma_f32_16x16x32_bf16(
                                      a[mt], b[sp][nt], acc[mt][nt], 0, 0, 0);
        }
    }

    // ---- epilogue: fp8-encode into LDS (transpose), then coalesced stores
    __syncthreads();                    // all waves done reading As
    unsigned char* ep = (unsigned char*)As;   // [64][EP_PITCH] bytes, 17 KB
    #pragma unroll
    for (int nt = 0; nt < 4; ++nt) {
        const int col  = wv * 64 + nt * 16 + m;
        const float bias = (col < 128) ? bq[col] : bk[col - 128];
        #pragma unroll
        for (int mt = 0; mt < 4; ++mt) {
            #pragma unroll
            for (int r = 0; r < 4; ++r) {
                const int rl = mt * 16 + q * 4 + r;
                const float v = acc[mt][nt][r] + bias;
                const int pk = __builtin_amdgcn_cvt_pk_fp8_f32(v, v, 0, false);
                ep[rl * EP_PITCH + col] = (unsigned char)(pk & 0xFF);
            }
        }
    }
    __syncthreads();
    {
        const int rl = tid >> 2;              // 0..63
        const int ch = tid & 3;               // 64-B chunk
        const int grow = mbase + rl;
        if (grow < N_NODES) {
            const uint4* s4 = (const uint4*)(ep + rl * EP_PITCH + ch * 64);
            const uint4 t0 = s4[0], t1 = s4[1], t2 = s4[2], t3 = s4[3];
            uint4* g = (uint4*)(qk8 + (size_t)grow * QKDIM + ch * 64);
            g[0] = t0; g[1] = t1; g[2] = t2; g[3] = t3;
        }
    }
}

// ---------------- Edge scoring + scatter (fp8 gather) ----------------
// [exact R4 known-good kernel: 95 us]
// 4 lanes per edge, 16 edges per wave. Lane j covers src bytes [64j, +64);
// dst bytes 64*((j+2)&3) (the (t+128)&255 q|k rotation).
__global__ __launch_bounds__(256) void edge_kernel(
    const unsigned char* __restrict__ qk8,
    const int* __restrict__ edge_index,   // [2][E]
    const int* __restrict__ d0,           // d0_index row 1, [2E]
    float* __restrict__ out)              // [0..N)=diagA0 (pre-zeroed), [N..N+E)=diagA1
{
    const int wave = (blockIdx.x * blockDim.x + threadIdx.x) >> 6;
    const int lane = threadIdx.x & 63;
    const int g = lane >> 2;              // edge within wave (0..15)
    const int j = lane & 3;               // lane within edge
    const int e = wave * 16 + g;          // 800000 = 50000*16, no tail

    const int src = edge_index[e];
    const int dst = edge_index[N_EDGES + e];

    const uint4* rs = (const uint4*)(qk8 + (size_t)src * QKDIM + 64 * j);
    const uint4* rd = (const uint4*)(qk8 + (size_t)dst * QKDIM + 64 * ((j + 2) & 3));

    uint4 a[4], b[4];
    #pragma unroll
    for (int i = 0; i < 4; ++i) { a[i] = rs[i]; b[i] = rd[i]; }

    float p = 0.f;
    #pragma unroll
    for (int i = 0; i < 4; ++i) {
        const unsigned int* ua = (const unsigned int*)&a[i];
        const unsigned int* ub = (const unsigned int*)&b[i];
        #pragma unroll
        for (int t = 0; t < 4; ++t) {
            const f2 x0 = __builtin_amdgcn_cvt_pk_f32_fp8(ua[t], false);
            const f2 y0 = __builtin_amdgcn_cvt_pk_f32_fp8(ub[t], false);
            const f2 x1 = __builtin_amdgcn_cvt_pk_f32_fp8(ua[t], true);
            const f2 y1 = __builtin_amdgcn_cvt_pk_f32_fp8(ub[t], true);
            p += x0[0] * y0[0] + x0[1] * y0[1] + x1[0] * y1[0] + x1[1] * y1[1];
        }
    }

    // reduce across the 4 lanes of this edge group
    p += __shfl_xor(p, 1, 64);
    p += __shfl_xor(p, 2, 64);

    if (j < 2) {
        const float val = __expf(p * 0.0625f);   // /16 = 0.5 * mean over 8 heads
        const int target = d0[2 * e + j];
        if (j == 0) out[N_NODES + e] = val;      // diagA1
        atomicAdd(&out[target], val);
    }
}

extern "C" void kernel_launch(void* const* d_in, const int* in_sizes, int n_in,
                              void* d_out, int out_size, void* d_ws, size_t ws_size,
                              hipStream_t stream) {
    const float* x  = (const float*)d_in[0];
    const float* Wq = (const float*)d_in[1];
    const float* bq = (const float*)d_in[2];
    const float* Wk = (const float*)d_in[3];
    const float* bk = (const float*)d_in[4];
    const int* edge_index = (const int*)d_in[5];
    const int* d0 = (const int*)d_in[6] + 2 * N_EDGES;  // row 1 of d0_index
    float* out = (float*)d_out;

    unsigned char* qk8 = (unsigned char*)d_ws;          // 12.8 MB

    proj_mfma<<<(N_NODES + 63) / 64, 256, 0, stream>>>(x, Wq, bq, Wk, bk, qk8, out);

    // 4 lanes/edge, 16 edges/wave, 4 waves/block -> 64 edges/block
    edge_kernel<<<N_EDGES / 64, 256, 0, stream>>>(qk8, edge_index, d0, out);
}

// Round 9
// 218.595 us; speedup vs baseline: 1.1361x; 1.0404x over previous
//
#include <hip/hip_runtime.h>
#include <hip/hip_bf16.h>

#define N_NODES 50000
#define N_EDGES 800000
#define DIM 256      // input feature dim = K
#define QKDIM 256    // packed q|k per node (fp8: 256 B/row)
// pre = (0.5/H) * sum_A (q_s k_d + q_d k_s) = (full rotated 256-dot)/16

typedef __bf16 bfrag  __attribute__((ext_vector_type(8)));
typedef __bf16 bf4    __attribute__((ext_vector_type(4)));
typedef float  ffrag  __attribute__((ext_vector_type(4)));
typedef float  f2     __attribute__((ext_vector_type(2)));

#define EP_PITCH 272   // epilogue LDS byte pitch (256+16)
#define EDGE_ITER 4    // groups of 16 edges per wave (pipelined)

// ---------------- prep: W' fp32->bf16 + zero diagA0 region ----------------
// [R6 known-good: ~4 us; doing this once beats per-block in-register cvt (R8 -12us)]
__global__ __launch_bounds__(256) void prep_kernel(
    const float* __restrict__ Wq, const float* __restrict__ Wk,
    __bf16* __restrict__ Wb, float* __restrict__ out)
{
    const int tid = blockIdx.x * 256 + threadIdx.x;   // 0..16383
    const int i = tid * 4;                            // 65536 elems total
    const float* s = (i < 32768) ? (Wq + i) : (Wk + (i - 32768));
    const float4 v = *(const float4*)s;
    bf4 o;
    o[0] = (__bf16)v.x; o[1] = (__bf16)v.y; o[2] = (__bf16)v.z; o[3] = (__bf16)v.w;
    *(bf4*)(Wb + i) = o;

    if (i + 4 <= N_NODES)   // 50000 % 4 == 0, covers exactly
        *(float4*)(out + i) = make_float4(0.f, 0.f, 0.f, 0.f);
}

// ---------------- Projection via MFMA bf16 ----------------
// [R6 known-good: ~19 us]
// Block: 64 nodes x 256 cols, 4 waves; wave wv covers cols [64wv, 64wv+64).
// A staged in LDS in fragment order; B (bf16 Wb) preloaded to regs per K-half;
// epilogue via LDS transpose -> coalesced dwordx4 stores.
__global__ __launch_bounds__(256) void proj_mfma(
    const float* __restrict__ x,
    const __bf16* __restrict__ Wb,
    const float* __restrict__ bq, const float* __restrict__ bk,
    unsigned char* __restrict__ qk8)
{
    __shared__ __bf16 As[64 * 256];   // 32 KB, fragment-order; reused by epilogue

    const int tid  = threadIdx.x;
    const int wv   = tid >> 6;         // 0..3 -> 64-col slice
    const int lane = tid & 63;
    const int m    = lane & 15;
    const int q    = lane >> 4;
    const int mbase = blockIdx.x * 64;

    // ---- stage A (64 rows x 256 k fp32 -> bf16 frags) ----
    {
        const int srow = tid >> 2;           // 0..63
        const int c4   = tid & 3;
        int grow = mbase + srow;
        grow = grow < N_NODES ? grow : N_NODES - 1;
        const float* xp = x + (size_t)grow * DIM;
        const int mt_ = srow >> 4, m_ = srow & 15;
        #pragma unroll
        for (int i = 0; i < 16; ++i) {
            const int k = c4 * 4 + 16 * i;
            const float4 v = *(const float4*)(xp + k);
            bf4 o;
            o[0] = (__bf16)v.x; o[1] = (__bf16)v.y;
            o[2] = (__bf16)v.z; o[3] = (__bf16)v.w;
            const int seg = (k >> 5) * 4 + mt_;
            const int ln  = ((k >> 3) & 3) * 16 + m_;
            *(bf4*)(As + seg * 512 + ln * 8 + (k & 7)) = o;
        }
    }
    __syncthreads();

    ffrag acc[4][4] = {};              // [m-tile][n-tile]

    #pragma unroll
    for (int h = 0; h < 2; ++h) {
        bfrag b[4][4];                 // [k-step][n-tile]
        #pragma unroll
        for (int sp = 0; sp < 4; ++sp)
            #pragma unroll
            for (int nt = 0; nt < 4; ++nt) {
                const int col = wv * 64 + nt * 16 + m;
                b[sp][nt] = *(const bfrag*)(Wb + (size_t)col * DIM
                                            + 32 * (4 * h + sp) + 8 * q);
            }
        #pragma unroll
        for (int sp = 0; sp < 4; ++sp) {
            bfrag a[4];
            #pragma unroll
            for (int mt = 0; mt < 4; ++mt)
                a[mt] = *(const bfrag*)(As + ((4 * h + sp) * 4 + mt) * 512 + lane * 8);
            #pragma unroll
            for (int mt = 0; mt < 4; ++mt)
                #pragma unroll
                for (int nt = 0; nt < 4; ++nt)
                    acc[mt][nt] = __builtin_amdgcn_mfma_f32_16x16x32_bf16(
                                      a[mt], b[sp][nt], acc[mt][nt], 0, 0, 0);
        }
    }

    // ---- epilogue: fp8-encode into LDS (transpose), then coalesced stores
    __syncthreads();                    // all waves done reading As
    unsigned char* ep = (unsigned char*)As;   // [64][EP_PITCH] bytes, 17 KB
    #pragma unroll
    for (int nt = 0; nt < 4; ++nt) {
        const int col  = wv * 64 + nt * 16 + m;
        const float bias = (col < 128) ? bq[col] : bk[col - 128];
        #pragma unroll
        for (int mt = 0; mt < 4; ++mt) {
            #pragma unroll
            for (int r = 0; r < 4; ++r) {
                const int rl = mt * 16 + q * 4 + r;
                const float v = acc[mt][nt][r] + bias;
                const int pk = __builtin_amdgcn_cvt_pk_fp8_f32(v, v, 0, false);
                ep[rl * EP_PITCH + col] = (unsigned char)(pk & 0xFF);
            }
        }
    }
    __syncthreads();
    {
        const int rl = tid >> 2;              // 0..63
        const int ch = tid & 3;               // 64-B chunk
        const int grow = mbase + rl;
        if (grow < N_NODES) {
            const uint4* s4 = (const uint4*)(ep + rl * EP_PITCH + ch * 64);
            const uint4 t0 = s4[0], t1 = s4[1], t2 = s4[2], t3 = s4[3];
            uint4* g = (uint4*)(qk8 + (size_t)grow * QKDIM + ch * 64);
            g[0] = t0; g[1] = t1; g[2] = t2; g[3] = t3;
        }
    }
}

// ---------------- Edge scoring + scatter (fp8, pipelined grid-stride) ------
// Same 4-lane/edge, 16-edges/group shape as R4 (known-good coalescing), but
// each wave runs EDGE_ITER groups with next-group row loads issued before the
// current group's reduce/exp/atomic -> 2x in-flight row fetches per wave.
__global__ __launch_bounds__(256) void edge_kernel(
    const unsigned char* __restrict__ qk8,
    const int* __restrict__ edge_index,   // [2][E]
    const int* __restrict__ d0,           // d0_index row 1, [2E]
    float* __restrict__ out)              // [0..N)=diagA0 (pre-zeroed), [N..N+E)=diagA1
{
    const int wid  = (blockIdx.x * blockDim.x + threadIdx.x) >> 6;
    const int lane = threadIdx.x & 63;
    const int g = lane >> 2;              // edge within group (0..15)
    const int j = lane & 3;               // lane within edge
    const int ebase = wid * (16 * EDGE_ITER) + g;   // wave's first-edge for g

    uint4 a[4], b[4];                     // current group's rows
    int2 tg;                              // current group's scatter targets

    // prologue: issue loads for iter 0
    {
        const int e = ebase;
        const int src = edge_index[e];
        const int dst = edge_index[N_EDGES + e];
        const uint4* rs = (const uint4*)(qk8 + (size_t)src * QKDIM + 64 * j);
        const uint4* rd = (const uint4*)(qk8 + (size_t)dst * QKDIM + 64 * ((j + 2) & 3));
        #pragma unroll
        for (int i = 0; i < 4; ++i) { a[i] = rs[i]; b[i] = rd[i]; }
        tg = *(const int2*)(d0 + 2 * e);
    }

    #pragma unroll
    for (int it = 0; it < EDGE_ITER; ++it) {
        uint4 a2[4], b2[4];
        int2 tg2;
        if (it + 1 < EDGE_ITER) {         // prefetch next group
            const int e2 = ebase + (it + 1) * 16;
            const int src = edge_index[e2];
            const int dst = edge_index[N_EDGES + e2];
            const uint4* rs = (const uint4*)(qk8 + (size_t)src * QKDIM + 64 * j);
            const uint4* rd = (const uint4*)(qk8 + (size_t)dst * QKDIM + 64 * ((j + 2) & 3));
            #pragma unroll
            for (int i = 0; i < 4; ++i) { a2[i] = rs[i]; b2[i] = rd[i]; }
            tg2 = *(const int2*)(d0 + 2 * e2);
        }

        float p = 0.f;
        #pragma unroll
        for (int i = 0; i < 4; ++i) {
            const unsigned int* ua = (const unsigned int*)&a[i];
            const unsigned int* ub = (const unsigned int*)&b[i];
            #pragma unroll
            for (int t = 0; t < 4; ++t) {
                const f2 x0 = __builtin_amdgcn_cvt_pk_f32_fp8(ua[t], false);
                const f2 y0 = __builtin_amdgcn_cvt_pk_f32_fp8(ub[t], false);
                const f2 x1 = __builtin_amdgcn_cvt_pk_f32_fp8(ua[t], true);
                const f2 y1 = __builtin_amdgcn_cvt_pk_f32_fp8(ub[t], true);
                p += x0[0] * y0[0] + x0[1] * y0[1] + x1[0] * y1[0] + x1[1] * y1[1];
            }
        }
        p += __shfl_xor(p, 1, 64);
        p += __shfl_xor(p, 2, 64);

        if (j < 2) {
            const float val = __expf(p * 0.0625f);   // /16 = 0.5*mean over heads
            const int e = ebase + it * 16;
            const int target = (j == 0) ? tg.x : tg.y;
            if (j == 0) out[N_NODES + e] = val;      // diagA1, 16 consecutive
            atomicAdd(&out[target], val);
        }

        if (it + 1 < EDGE_ITER) {
            #pragma unroll
            for (int i = 0; i < 4; ++i) { a[i] = a2[i]; b[i] = b2[i]; }
            tg = tg2;
        }
    }
}

extern "C" void kernel_launch(void* const* d_in, const int* in_sizes, int n_in,
                              void* d_out, int out_size, void* d_ws, size_t ws_size,
                              hipStream_t stream) {
    const float* x  = (const float*)d_in[0];
    const float* Wq = (const float*)d_in[1];
    const float* bq = (const float*)d_in[2];
    const float* Wk = (const float*)d_in[3];
    const float* bk = (const float*)d_in[4];
    const int* edge_index = (const int*)d_in[5];
    const int* d0 = (const int*)d_in[6] + 2 * N_EDGES;  // row 1 of d0_index
    float* out = (float*)d_out;

    unsigned char* qk8 = (unsigned char*)d_ws;                       // 12.8 MB
    __bf16* Wb = (__bf16*)((char*)d_ws + (size_t)N_NODES * QKDIM);   // +128 KB

    prep_kernel<<<64, 256, 0, stream>>>(Wq, Wk, Wb, out);
    proj_mfma<<<(N_NODES + 63) / 64, 256, 0, stream>>>(x, Wb, bq, bk, qk8);

    // 4 waves/block x EDGE_ITER groups x 16 edges = 256 edges/block
    edge_kernel<<<N_EDGES / (64 * EDGE_ITER), 256, 0, stream>>>(qk8, edge_index, d0, out);
}

// Round 10
// 215.725 us; speedup vs baseline: 1.1512x; 1.0133x over previous
//
#include <hip/hip_runtime.h>
#include <hip/hip_bf16.h>

#define N_NODES 50000
#define N_EDGES 800000
#define DIM 256      // input feature dim = K
#define QKDIM 256    // packed q|k per node (fp8: 256 B/row)
// pre = (0.5/H) * sum_A (q_s k_d + q_d k_s) = (full rotated 256-dot)/16
//
// FINAL STRUCTURE (best measured, R6):
//   prep (4 us)  : W fp32->bf16 once + zero diagA0  [per-block cvt regressed: R8]
//   proj (19 us) : MFMA bf16 64x256 tile, LDS-staged A, reg-B, LDS-transpose
//                  fp8 epilogue  [scattered byte-store epilogue regressed: R2-R5]
//   edge (95 us) : 4 lanes/edge fp8 row-gather — pattern floor at ~2.1 TB/s
//                  random-line miss path [2-lane (R7) and pipelined (R9) neutral/worse]
//   + ~96 us fixed harness floor (gaps/restores, invariant R1-R9)

typedef __bf16 bfrag  __attribute__((ext_vector_type(8)));
typedef __bf16 bf4    __attribute__((ext_vector_type(4)));
typedef float  ffrag  __attribute__((ext_vector_type(4)));
typedef float  f2     __attribute__((ext_vector_type(2)));

#define EP_PITCH 272   // epilogue LDS byte pitch (256+16)

// ---------------- prep: W' fp32->bf16 + zero diagA0 region ----------------
__global__ __launch_bounds__(256) void prep_kernel(
    const float* __restrict__ Wq, const float* __restrict__ Wk,
    __bf16* __restrict__ Wb, float* __restrict__ out)
{
    const int tid = blockIdx.x * 256 + threadIdx.x;   // 0..16383
    const int i = tid * 4;                            // 65536 elems total
    const float* s = (i < 32768) ? (Wq + i) : (Wk + (i - 32768));
    const float4 v = *(const float4*)s;
    bf4 o;
    o[0] = (__bf16)v.x; o[1] = (__bf16)v.y; o[2] = (__bf16)v.z; o[3] = (__bf16)v.w;
    *(bf4*)(Wb + i) = o;

    if (i + 4 <= N_NODES)   // 50000 % 4 == 0, covers exactly
        *(float4*)(out + i) = make_float4(0.f, 0.f, 0.f, 0.f);
}

// ---------------- Projection via MFMA bf16 ----------------
// Block: 64 nodes x 256 cols, 4 waves; wave wv covers cols [64wv, 64wv+64).
__global__ __launch_bounds__(256) void proj_mfma(
    const float* __restrict__ x,
    const __bf16* __restrict__ Wb,
    const float* __restrict__ bq, const float* __restrict__ bk,
    unsigned char* __restrict__ qk8)
{
    __shared__ __bf16 As[64 * 256];   // 32 KB, fragment-order; reused by epilogue

    const int tid  = threadIdx.x;
    const int wv   = tid >> 6;         // 0..3 -> 64-col slice
    const int lane = tid & 63;
    const int m    = lane & 15;
    const int q    = lane >> 4;
    const int mbase = blockIdx.x * 64;

    // ---- stage A (64 rows x 256 k fp32 -> bf16 frags) ----
    {
        const int srow = tid >> 2;           // 0..63
        const int c4   = tid & 3;
        int grow = mbase + srow;
        grow = grow < N_NODES ? grow : N_NODES - 1;
        const float* xp = x + (size_t)grow * DIM;
        const int mt_ = srow >> 4, m_ = srow & 15;
        #pragma unroll
        for (int i = 0; i < 16; ++i) {
            const int k = c4 * 4 + 16 * i;
            const float4 v = *(const float4*)(xp + k);
            bf4 o;
            o[0] = (__bf16)v.x; o[1] = (__bf16)v.y;
            o[2] = (__bf16)v.z; o[3] = (__bf16)v.w;
            const int seg = (k >> 5) * 4 + mt_;
            const int ln  = ((k >> 3) & 3) * 16 + m_;
            *(bf4*)(As + seg * 512 + ln * 8 + (k & 7)) = o;
        }
    }
    __syncthreads();

    ffrag acc[4][4] = {};              // [m-tile][n-tile]

    #pragma unroll
    for (int h = 0; h < 2; ++h) {
        bfrag b[4][4];                 // [k-step][n-tile]
        #pragma unroll
        for (int sp = 0; sp < 4; ++sp)
            #pragma unroll
            for (int nt = 0; nt < 4; ++nt) {
                const int col = wv * 64 + nt * 16 + m;
                b[sp][nt] = *(const bfrag*)(Wb + (size_t)col * DIM
                                            + 32 * (4 * h + sp) + 8 * q);
            }
        #pragma unroll
        for (int sp = 0; sp < 4; ++sp) {
            bfrag a[4];
            #pragma unroll
            for (int mt = 0; mt < 4; ++mt)
                a[mt] = *(const bfrag*)(As + ((4 * h + sp) * 4 + mt) * 512 + lane * 8);
            #pragma unroll
            for (int mt = 0; mt < 4; ++mt)
                #pragma unroll
                for (int nt = 0; nt < 4; ++nt)
                    acc[mt][nt] = __builtin_amdgcn_mfma_f32_16x16x32_bf16(
                                      a[mt], b[sp][nt], acc[mt][nt], 0, 0, 0);
        }
    }

    // ---- epilogue: fp8-encode into LDS (transpose), then coalesced stores
    __syncthreads();                    // all waves done reading As
    unsigned char* ep = (unsigned char*)As;   // [64][EP_PITCH] bytes, 17 KB
    #pragma unroll
    for (int nt = 0; nt < 4; ++nt) {
        const int col  = wv * 64 + nt * 16 + m;
        const float bias = (col < 128) ? bq[col] : bk[col - 128];
        #pragma unroll
        for (int mt = 0; mt < 4; ++mt) {
            #pragma unroll
            for (int r = 0; r < 4; ++r) {
                const int rl = mt * 16 + q * 4 + r;
                const float v = acc[mt][nt][r] + bias;
                const int pk = __builtin_amdgcn_cvt_pk_fp8_f32(v, v, 0, false);
                ep[rl * EP_PITCH + col] = (unsigned char)(pk & 0xFF);
            }
        }
    }
    __syncthreads();
    {
        const int rl = tid >> 2;              // 0..63
        const int ch = tid & 3;               // 64-B chunk
        const int grow = mbase + rl;
        if (grow < N_NODES) {
            const uint4* s4 = (const uint4*)(ep + rl * EP_PITCH + ch * 64);
            const uint4 t0 = s4[0], t1 = s4[1], t2 = s4[2], t3 = s4[3];
            uint4* g = (uint4*)(qk8 + (size_t)grow * QKDIM + ch * 64);
            g[0] = t0; g[1] = t1; g[2] = t2; g[3] = t3;
        }
    }
}

// ---------------- Edge scoring + scatter (fp8 gather) ----------------
// [exact R4 known-good kernel: 95 us — measured pattern floor]
// 4 lanes per edge, 16 edges per wave. Lane j covers src bytes [64j, +64);
// dst bytes 64*((j+2)&3) (the (t+128)&255 q|k rotation).
__global__ __launch_bounds__(256) void edge_kernel(
    const unsigned char* __restrict__ qk8,
    const int* __restrict__ edge_index,   // [2][E]
    const int* __restrict__ d0,           // d0_index row 1, [2E]
    float* __restrict__ out)              // [0..N)=diagA0 (pre-zeroed), [N..N+E)=diagA1
{
    const int wave = (blockIdx.x * blockDim.x + threadIdx.x) >> 6;
    const int lane = threadIdx.x & 63;
    const int g = lane >> 2;              // edge within wave (0..15)
    const int j = lane & 3;               // lane within edge
    const int e = wave * 16 + g;          // 800000 = 50000*16, no tail

    const int src = edge_index[e];
    const int dst = edge_index[N_EDGES + e];

    const uint4* rs = (const uint4*)(qk8 + (size_t)src * QKDIM + 64 * j);
    const uint4* rd = (const uint4*)(qk8 + (size_t)dst * QKDIM + 64 * ((j + 2) & 3));

    uint4 a[4], b[4];
    #pragma unroll
    for (int i = 0; i < 4; ++i) { a[i] = rs[i]; b[i] = rd[i]; }

    float p = 0.f;
    #pragma unroll
    for (int i = 0; i < 4; ++i) {
        const unsigned int* ua = (const unsigned int*)&a[i];
        const unsigned int* ub = (const unsigned int*)&b[i];
        #pragma unroll
        for (int t = 0; t < 4; ++t) {
            const f2 x0 = __builtin_amdgcn_cvt_pk_f32_fp8(ua[t], false);
            const f2 y0 = __builtin_amdgcn_cvt_pk_f32_fp8(ub[t], false);
            const f2 x1 = __builtin_amdgcn_cvt_pk_f32_fp8(ua[t], true);
            const f2 y1 = __builtin_amdgcn_cvt_pk_f32_fp8(ub[t], true);
            p += x0[0] * y0[0] + x0[1] * y0[1] + x1[0] * y1[0] + x1[1] * y1[1];
        }
    }

    // reduce across the 4 lanes of this edge group
    p += __shfl_xor(p, 1, 64);
    p += __shfl_xor(p, 2, 64);

    if (j < 2) {
        const float val = __expf(p * 0.0625f);   // /16 = 0.5 * mean over 8 heads
        const int target = d0[2 * e + j];
        if (j == 0) out[N_NODES + e] = val;      // diagA1
        atomicAdd(&out[target], val);
    }
}

extern "C" void kernel_launch(void* const* d_in, const int* in_sizes, int n_in,
                              void* d_out, int out_size, void* d_ws, size_t ws_size,
                              hipStream_t stream) {
    const float* x  = (const float*)d_in[0];
    const float* Wq = (const float*)d_in[1];
    const float* bq = (const float*)d_in[2];
    const float* Wk = (const float*)d_in[3];
    const float* bk = (const float*)d_in[4];
    const int* edge_index = (const int*)d_in[5];
    const int* d0 = (const int*)d_in[6] + 2 * N_EDGES;  // row 1 of d0_index
    float* out = (float*)d_out;

    unsigned char* qk8 = (unsigned char*)d_ws;                       // 12.8 MB
    __bf16* Wb = (__bf16*)((char*)d_ws + (size_t)N_NODES * QKDIM);   // +128 KB

    prep_kernel<<<64, 256, 0, stream>>>(Wq, Wk, Wb, out);
    proj_mfma<<<(N_NODES + 63) / 64, 256, 0, stream>>>(x, Wb, bq, bk, qk8);

    // 4 lanes/edge, 16 edges/wave, 4 waves/block -> 64 edges/block
    edge_kernel<<<N_EDGES / 64, 256, 0, stream>>>(qk8, edge_index, d0, out);
}